// Round 8
// baseline (402.361 us; speedup 1.0000x reference)
//
#include <hip/hip_runtime.h>
#include <stdint.h>
#include <stddef.h>

typedef unsigned short u16;
typedef __bf16 bf16x8 __attribute__((ext_vector_type(8)));
typedef float floatx4 __attribute__((ext_vector_type(4)));

#define B_  4
#define S_  2048
#define D_  1024
#define H_  16
#define DH_ 64

__device__ __forceinline__ float b2f(u16 u) {
  union { unsigned u; float f; } c; c.u = ((unsigned)u) << 16; return c.f;
}
__device__ __forceinline__ u16 f2b(float f) {
  union { float f; unsigned u; } c; c.f = f;
  unsigned u = c.u;
  u += 0x7fffu + ((u >> 16) & 1u);   // round-to-nearest-even
  return (u16)(u >> 16);
}

// async global->LDS, 16B per lane. LDS dest: wave-uniform base + lane*16.
__device__ __forceinline__ void gld_lds16(const u16* g, u16* l) {
  __builtin_amdgcn_global_load_lds(
      (const __attribute__((address_space(1))) unsigned int*)g,
      (__attribute__((address_space(3))) unsigned int*)l, 16, 0, 0);
}

// pack two f32 -> one u32 of 2 bf16 (no builtin on gfx950; T12 recipe)
__device__ __forceinline__ unsigned cvtpk(float lo, float hi) {
  unsigned r;
  asm("v_cvt_pk_bf16_f32 %0, %1, %2" : "=v"(r) : "v"(lo), "v"(hi));
  return r;
}

// raw v_exp_f32: r = 2^x (ISA §3). Caller pre-scales by log2e.
__device__ __forceinline__ float fexp2(float x) {
  float r; asm("v_exp_f32 %0, %1" : "=v"(r) : "v"(x)); return r;
}

// permlane swaps: diagonal transpose of (reg-index, lane-bit) 2x2
#define PL32(a, b) asm("v_permlane32_swap_b32 %0, %1" : "+v"(a), "+v"(b))
#define PL16(a, b) asm("v_permlane16_swap_b32 %0, %1" : "+v"(a), "+v"(b))

union B8 { unsigned u[4]; bf16x8 v; };

// ---------------------------------------------------------------------------
// Kernel 0: fp32 -> bf16 convert (for weights). n must be a multiple of 4.
// ---------------------------------------------------------------------------
__global__ __launch_bounds__(256) void cvt_f32_bf16(
    const float* __restrict__ src, u16* __restrict__ dst, int n)
{
  int i = (blockIdx.x * 256 + threadIdx.x) * 4;
  if (i >= n) return;
  float4 v = *(const float4*)(src + i);
  u16 o[4] __attribute__((aligned(8)));
  o[0] = f2b(v.x); o[1] = f2b(v.y); o[2] = f2b(v.z); o[3] = f2b(v.w);
  *(uint2*)(dst + i) = *(uint2*)o;
}

// ---------------------------------------------------------------------------
// Kernel 1: LayerNorm + pos_emb add. fp32 in, bf16 out. One block per row.
// ---------------------------------------------------------------------------
__global__ __launch_bounds__(256) void ln_pos_kernel(
    const float* __restrict__ x, const float* __restrict__ pos,
    const float* __restrict__ gamma, const float* __restrict__ beta,
    u16* __restrict__ xp)
{
  const int row = blockIdx.x;
  const int s = row & (S_ - 1);
  const int t = threadIdx.x;
  const int lane = t & 63, w = t >> 6;

  float4 xv = *(const float4*)(x + (size_t)row * D_ + t * 4);
  float f[4] = {xv.x, xv.y, xv.z, xv.w};
  float sum = f[0] + f[1] + f[2] + f[3];
  float sq  = f[0]*f[0] + f[1]*f[1] + f[2]*f[2] + f[3]*f[3];
#pragma unroll
  for (int m = 1; m < 64; m <<= 1) {
    sum += __shfl_xor(sum, m);
    sq  += __shfl_xor(sq, m);
  }
  __shared__ float red[8];
  if (lane == 0) { red[w] = sum; red[4 + w] = sq; }
  __syncthreads();
  sum = red[0] + red[1] + red[2] + red[3];
  sq  = red[4] + red[5] + red[6] + red[7];
  const float mu = sum * (1.f / D_);
  const float rstd = rsqrtf(fmaxf(sq * (1.f / D_) - mu * mu, 0.f) + 1e-5f);

  float4 gv = *(const float4*)(gamma + t * 4);
  float4 bv = *(const float4*)(beta + t * 4);
  float4 pv = *(const float4*)(pos + (size_t)s * D_ + t * 4);
  float g[4] = {gv.x, gv.y, gv.z, gv.w};
  float bb[4] = {bv.x, bv.y, bv.z, bv.w};
  float pp[4] = {pv.x, pv.y, pv.z, pv.w};
  u16 ov[4] __attribute__((aligned(8)));
#pragma unroll
  for (int i = 0; i < 4; ++i)
    ov[i] = f2b((f[i] - mu) * rstd * g[i] + bb[i] + pp[i]);
  *(uint2*)(xp + (size_t)row * D_ + t * 4) = *(uint2*)ov;
}

// ---------------------------------------------------------------------------
// Kernel 2: C[M,N] = A[M,K] @ B[N,K]^T (+bias[N]) (+res[M,N]); bf16 A/B,
// fp32 acc. 128x128 tile, BK=32, 4 waves, double-buffered (R6), XCD swizzle
// (R7). Used for k4/k5 (their 256^2 grids would be 128 blocks = half idle).
// ---------------------------------------------------------------------------
template<int HAS_BIAS, int HAS_RES, int OUT_F32>
__global__ __launch_bounds__(256) void gemm_bt(
    const u16* A, const u16* __restrict__ Bm,
    const float* __restrict__ bias, const u16* res,
    void* Cv, int M, int N, int K, int lda, int ldc)
{
  __shared__ u16 As[2][128 * 32];
  __shared__ u16 Bs[2][128 * 32];
  const int tid = threadIdx.x;
  const int lane = tid & 63, w = tid >> 6;
  const int quad = lane >> 4, l4 = lane & 15;
  const int wm = (w >> 1) * 64, wn = (w & 1) * 64;

  // XCD-aware bijective remap (nwg % 8 == 0 for all launches)
  const int gx = gridDim.x;
  int lin = blockIdx.y * gx + blockIdx.x;
  lin = (lin & 7) * ((gx * gridDim.y) >> 3) + (lin >> 3);
  const int m0 = (lin / gx) * 128, n0 = (lin % gx) * 128;

  const u16* Ag = A + (size_t)m0 * lda;
  const u16* Bg = Bm + (size_t)n0 * K;

  const int s0 = tid, s1 = tid + 256;
  const int r0 = s0 >> 2, c0 = ((s0 & 3) - (r0 >> 1)) & 3;
  const int r1 = s1 >> 2, c1 = ((s1 & 3) - (r1 >> 1)) & 3;
  const int pA = (quad + (l4 >> 1)) & 3;   // frag-read swizzled chunk position

  floatx4 acc[4][4] = {};

  const int nk = K >> 5;
  gld_lds16(Ag + (size_t)r0 * lda + c0 * 8, &As[0][s0 * 8]);
  gld_lds16(Ag + (size_t)r1 * lda + c1 * 8, &As[0][s1 * 8]);
  gld_lds16(Bg + (size_t)r0 * K + c0 * 8, &Bs[0][s0 * 8]);
  gld_lds16(Bg + (size_t)r1 * K + c1 * 8, &Bs[0][s1 * 8]);
  __syncthreads();

  for (int kk = 0; kk < nk; ++kk) {
    const int cur = kk & 1;
    if (kk + 1 < nk) {
      const int k0 = (kk + 1) << 5;
      gld_lds16(Ag + (size_t)r0 * lda + k0 + c0 * 8, &As[cur ^ 1][s0 * 8]);
      gld_lds16(Ag + (size_t)r1 * lda + k0 + c1 * 8, &As[cur ^ 1][s1 * 8]);
      gld_lds16(Bg + (size_t)r0 * K + k0 + c0 * 8, &Bs[cur ^ 1][s0 * 8]);
      gld_lds16(Bg + (size_t)r1 * K + k0 + c1 * 8, &Bs[cur ^ 1][s1 * 8]);
    }
    bf16x8 af[4], bfr[4];
#pragma unroll
    for (int i = 0; i < 4; ++i)
      af[i] = *(const bf16x8*)&As[cur][(wm + i * 16 + l4) * 32 + pA * 8];
#pragma unroll
    for (int j = 0; j < 4; ++j)
      bfr[j] = *(const bf16x8*)&Bs[cur][(wn + j * 16 + l4) * 32 + pA * 8];
#pragma unroll
    for (int i = 0; i < 4; ++i)
#pragma unroll
      for (int j = 0; j < 4; ++j)
        acc[i][j] = __builtin_amdgcn_mfma_f32_16x16x32_bf16(af[i], bfr[j], acc[i][j], 0, 0, 0);
    __syncthreads();   // next tile staged + everyone done reading cur
  }

#pragma unroll
  for (int i = 0; i < 4; ++i) {
#pragma unroll
    for (int j = 0; j < 4; ++j) {
      const int col = n0 + wn + j * 16 + l4;
      float bvv = 0.f;
      if (HAS_BIAS) bvv = bias[col];
#pragma unroll
      for (int r = 0; r < 4; ++r) {
        const int row = m0 + wm + i * 16 + quad * 4 + r;
        float v = acc[i][j][r] + bvv;
        if (HAS_RES) v += b2f(res[(size_t)row * ldc + col]);
        v = fminf(fmaxf(v, -60000.f), 60000.f);  // diagnostic fingerprint; no-op on valid data
        if (OUT_F32) ((float*)Cv)[(size_t)row * ldc + col] = v;
        else         ((u16*)Cv)[(size_t)row * ldc + col] = f2b(v);
      }
    }
  }
}

// ---------------------------------------------------------------------------
// Kernel 2b (R8): 256x256 tile, BK=32, 8 waves (512 thr, 2M x 4N, wave tile
// 128x64), 3-stage LDS pipeline with COUNTED vmcnt — never a full drain in
// steady state (evidence: m218 counted-vs-drain = the gain; m139 = counted
// vmcnt at 128^2/4-wave is null, structure matters). Per K-tile:
//   vmcnt(4)  -> tile t's 4 loads landed (t+1's 4 newest may float)
//   s_barrier -> all waves' staged data visible; all done reading buf[t-1]
//   STAGE t+2 -> buf[(t+2)%3] (== buf[(t-1)%3], free per the barrier)
//   2 phases x {4+4 ds_read_b128, setprio(1), 16 MFMA, setprio(0)}
// Chunk-rotation LDS swizzle + source-permuted global_load_lds are verbatim
// the proven 128^2 formulas. LDS 96 KB -> 1 block/CU (8 waves = 2/SIMD).
// ---------------------------------------------------------------------------
template<int HAS_BIAS, int HAS_RES, int OUT_F32>
__global__ __launch_bounds__(512, 2) void gemm_bt256(
    const u16* A, const u16* __restrict__ Bm,
    const float* __restrict__ bias, const u16* res,
    void* Cv, int M, int N, int K, int lda, int ldc)
{
  __shared__ u16 As[3][256 * 32];   // 48 KB
  __shared__ u16 Bs[3][256 * 32];   // 48 KB
  const int tid = threadIdx.x;
  const int lane = tid & 63, w = tid >> 6;
  const int quad = lane >> 4, l4 = lane & 15;
  const int wr = (w >> 2) * 128, wc = (w & 3) * 64;

  const int gx = gridDim.x;
  int lin = blockIdx.y * gx + blockIdx.x;
  lin = (lin & 7) * ((gx * gridDim.y) >> 3) + (lin >> 3);
  const int m0 = (lin / gx) * 256, n0 = (lin % gx) * 256;

  const u16* Ag = A + (size_t)m0 * lda;
  const u16* Bg = Bm + (size_t)n0 * K;

  // staging: 256x32 per matrix per tile = 2 gld/thread each (512 threads)
  const int s0 = tid, s1 = tid + 512;
  const int r0 = s0 >> 2, c0 = ((s0 & 3) - (r0 >> 1)) & 3;
  const int r1 = s1 >> 2, c1 = ((s1 & 3) - (r1 >> 1)) & 3;
  const int pA = (quad + (l4 >> 1)) & 3;   // frag-read swizzled chunk position

  floatx4 acc[8][4] = {};   // 128 VGPR

  const int nk = K >> 5;

#define STG256(kt, buf)                                                      \
  {                                                                          \
    const int k0 = (kt) << 5;                                                \
    gld_lds16(Ag + (size_t)r0 * lda + k0 + c0 * 8, &As[buf][s0 * 8]);        \
    gld_lds16(Ag + (size_t)r1 * lda + k0 + c1 * 8, &As[buf][s1 * 8]);        \
    gld_lds16(Bg + (size_t)r0 * K + k0 + c0 * 8, &Bs[buf][s0 * 8]);          \
    gld_lds16(Bg + (size_t)r1 * K + k0 + c1 * 8, &Bs[buf][s1 * 8]);          \
  }

  STG256(0, 0);
  STG256(1, 1);            // 8 loads outstanding

  for (int kk = 0; kk < nk; ++kk) {
    const int cur = kk % 3;
    if (kk + 2 < nk) { asm volatile("s_waitcnt vmcnt(4)" ::: "memory"); }
    else             { asm volatile("s_waitcnt vmcnt(0)" ::: "memory"); }
    asm volatile("s_barrier" ::: "memory");
    if (kk + 2 < nk) STG256(kk + 2, (kk + 2) % 3);

    bf16x8 bfr[4];
#pragma unroll
    for (int n = 0; n < 4; ++n)
      bfr[n] = *(const bf16x8*)&Bs[cur][(wc + n * 16 + l4) * 32 + pA * 8];
#pragma unroll
    for (int mh = 0; mh < 2; ++mh) {
      bf16x8 af[4];
#pragma unroll
      for (int mm = 0; mm < 4; ++mm)
        af[mm] = *(const bf16x8*)&As[cur][(wr + mh * 64 + mm * 16 + l4) * 32 + pA * 8];
      __builtin_amdgcn_s_setprio(1);
#pragma unroll
      for (int mm = 0; mm < 4; ++mm)
#pragma unroll
        for (int n = 0; n < 4; ++n)
          acc[mh * 4 + mm][n] = __builtin_amdgcn_mfma_f32_16x16x32_bf16(
              af[mm], bfr[n], acc[mh * 4 + mm][n], 0, 0, 0);
      __builtin_amdgcn_s_setprio(0);
    }
  }
#undef STG256

#pragma unroll
  for (int i = 0; i < 8; ++i) {
#pragma unroll
    for (int j = 0; j < 4; ++j) {
      const int col = n0 + wc + j * 16 + l4;
      float bvv = 0.f;
      if (HAS_BIAS) bvv = bias[col];
#pragma unroll
      for (int r = 0; r < 4; ++r) {
        const int row = m0 + wr + i * 16 + quad * 4 + r;
        float v = acc[i][j][r] + bvv;
        if (HAS_RES) v += b2f(res[(size_t)row * ldc + col]);
        v = fminf(fmaxf(v, -60000.f), 60000.f);  // no-op on valid data
        if (OUT_F32) ((float*)Cv)[(size_t)row * ldc + col] = v;
        else         ((u16*)Cv)[(size_t)row * ldc + col] = f2b(v);
      }
    }
  }
}

// ---------------------------------------------------------------------------
// Kernel 3: attention (R7-proven, unchanged). One block = (b, h, 128 Q rows),
// 4 waves, wave owns 32 Q rows. KV tile 64, double-buffered. Swapped QK^T,
// in-register softmax (exp2-fold), cvtpk+permlane P-exchange, MFMA rowsum.
// ---------------------------------------------------------------------------
__global__ __launch_bounds__(256, 3) void attn_kernel(
    u16* qkv, const float* __restrict__ mask)
{
  __shared__ u16 Ks[2][64 * 64];    // 2 x 8 KB, chunk-rotation swizzle
  __shared__ u16 Vt[2][64 * 72];    // 2 x 9 KB, V transposed, +8 pad

  const int tid = threadIdx.x;
  const int lane = tid & 63, w = tid >> 6;
  const int quad = lane >> 4, l4 = lane & 15;
  const int qb = blockIdx.x;           // 0..15
  const int bh = blockIdx.y;           // 0..63
  const int b = bh >> 4, h = bh & 15;
  const int q0 = qb * 128;

  const size_t rstr = 3 * D_;
  u16* qbase = qkv + (size_t)b * S_ * rstr + h * DH_;

  bf16x8 qfrag[2][2];
#pragma unroll
  for (int qi = 0; qi < 2; ++qi) {
    const u16* qp = qbase + (size_t)(q0 + w * 32 + qi * 16 + l4) * rstr + quad * 8;
    qfrag[qi][0] = *(const bf16x8*)(qp);
    qfrag[qi][1] = *(const bf16x8*)(qp + 32);
  }

  const u16* kbase0 = qkv + (size_t)b * S_ * rstr + D_ + h * DH_;
  const u16* vbase0 = kbase0 + D_;
  const int vs = tid & 63, vd0 = (tid >> 6) * 16;

  B8 ones;
  ones.u[0] = ones.u[1] = ones.u[2] = ones.u[3] = 0x3f803f80u;

  floatx4 acc_o[2][4] = {};
  floatx4 acc_l[2] = {};
  u16 vreg[16] __attribute__((aligned(16)));

  {
#pragma unroll
    for (int t = 0; t < 2; ++t) {
      int sidx = tid + t * 256;
      int rr = sidx >> 3, ch = ((sidx & 7) - rr) & 7;
      gld_lds16(kbase0 + (size_t)rr * rstr + ch * 8, &Ks[0][sidx * 8]);
    }
    const u16* vp = vbase0 + (size_t)vs * rstr + vd0;
    *(uint4*)(vreg)     = *(const uint4*)(vp);
    *(uint4*)(vreg + 8) = *(const uint4*)(vp + 8);
  }
  __syncthreads();
#pragma unroll
  for (int d = 0; d < 16; ++d) Vt[0][(vd0 + d) * 72 + vs] = vreg[d];
  __syncthreads();

  int cur = 0;
  for (int j = 0; j < 32; ++j) {
    if (j < 31) {
      const u16* vp = vbase0 + ((size_t)(j + 1) * 64 + vs) * rstr + vd0;
      *(uint4*)(vreg)     = *(const uint4*)(vp);
      *(uint4*)(vreg + 8) = *(const uint4*)(vp + 8);
      const u16* kb = kbase0 + (size_t)(j + 1) * 64 * rstr;
#pragma unroll
      for (int t = 0; t < 2; ++t) {
        int sidx = tid + t * 256;
        int rr = sidx >> 3, ch = ((sidx & 7) - rr) & 7;
        gld_lds16(kb + (size_t)rr * rstr + ch * 8, &Ks[cur ^ 1][sidx * 8]);
      }
    }

    floatx4 accs[2][4] = {};
#pragma unroll
    for (int kc = 0; kc < 2; ++kc)
#pragma unroll
      for (int tj = 0; tj < 4; ++tj) {
        const int rk = tj * 16 + l4;
        bf16x8 kf = *(const bf16x8*)&Ks[cur][rk * 64 + (((kc * 4 + quad) + rk) & 7) * 8];
        accs[0][tj] = __builtin_amdgcn_mfma_f32_16x16x32_bf16(kf, qfrag[0][kc], accs[0][tj], 0, 0, 0);
        accs[1][tj] = __builtin_amdgcn_mfma_f32_16x16x32_bf16(kf, qfrag[1][kc], accs[1][tj], 0, 0, 0);
      }

    const float* mrow = mask + (size_t)b * S_ + j * 64 + quad * 4;
    float mterm[4][4];
#pragma unroll
    for (int tj = 0; tj < 4; ++tj) {
      float4 mv = *(const float4*)(mrow + tj * 16);
      mterm[tj][0] = fmaf(mv.x, -1.44269504f, 1.44269504f);
      mterm[tj][1] = fmaf(mv.y, -1.44269504f, 1.44269504f);
      mterm[tj][2] = fmaf(mv.z, -1.44269504f, 1.44269504f);
      mterm[tj][3] = fmaf(mv.w, -1.44269504f, 1.44269504f);
    }
    unsigned pk[2][4][2];
#pragma unroll
    for (int qi = 0; qi < 2; ++qi) {
#pragma unroll
      for (int tj = 0; tj < 4; ++tj) {
        float p0 = fexp2(fminf(fmaf(accs[qi][tj][0], 0.18033688f, mterm[tj][0]), 43.3f));
        float p1 = fexp2(fminf(fmaf(accs[qi][tj][1], 0.18033688f, mterm[tj][1]), 43.3f));
        float p2 = fexp2(fminf(fmaf(accs[qi][tj][2], 0.18033688f, mterm[tj][2]), 43.3f));
        float p3 = fexp2(fminf(fmaf(accs[qi][tj][3], 0.18033688f, mterm[tj][3]), 43.3f));
        pk[qi][tj][0] = cvtpk(p0, p1);
        pk[qi][tj][1] = cvtpk(p2, p3);
      }
    }

#pragma unroll
    for (int kc = 0; kc < 2; ++kc) {
      bf16x8 bfr[4];
#pragma unroll
      for (int tn = 0; tn < 4; ++tn)
        bfr[tn] = *(const bf16x8*)&Vt[cur][(tn * 16 + l4) * 72 + kc * 32 + quad * 8];
#pragma unroll
      for (int qi = 0; qi < 2; ++qi) {
        unsigned x0 = pk[qi][2 * kc][0], x1 = pk[qi][2 * kc + 1][0];
        unsigned y0 = pk[qi][2 * kc][1], y1 = pk[qi][2 * kc + 1][1];
        PL32(x0, x1); PL32(y0, y1);
        PL16(x0, x1); PL16(y0, y1);
        B8 pa; pa.u[0] = x0; pa.u[1] = y0; pa.u[2] = x1; pa.u[3] = y1;
        __builtin_amdgcn_s_setprio(1);
#pragma unroll
        for (int tn = 0; tn < 4; ++tn)
          acc_o[qi][tn] = __builtin_amdgcn_mfma_f32_16x16x32_bf16(pa.v, bfr[tn], acc_o[qi][tn], 0, 0, 0);
        acc_l[qi] = __builtin_amdgcn_mfma_f32_16x16x32_bf16(pa.v, ones.v, acc_l[qi], 0, 0, 0);
        __builtin_amdgcn_s_setprio(0);
      }
    }

    if (j < 31) {
#pragma unroll
      for (int d = 0; d < 16; ++d) Vt[cur ^ 1][(vd0 + d) * 72 + vs] = vreg[d];
    }

    __syncthreads();
    cur ^= 1;
  }

#pragma unroll
  for (int qi = 0; qi < 2; ++qi) {
    float inv[4];
#pragma unroll
    for (int r = 0; r < 4; ++r) inv[r] = 1.0f / acc_l[qi][r];
#pragma unroll
    for (int tn = 0; tn < 4; ++tn) {
#pragma unroll
      for (int r = 0; r < 4; ++r) {
        const int row = q0 + w * 32 + qi * 16 + quad * 4 + r;
        const int col = h * DH_ + tn * 16 + l4;
        qkv[((size_t)b * S_ + row) * rstr + col] = f2b(acc_o[qi][tn][r] * inv[r]);
      }
    }
  }
}

// ---------------------------------------------------------------------------
extern "C" void kernel_launch(void* const* d_in, const int* in_sizes, int n_in,
                              void* d_out, int out_size, void* d_ws, size_t ws_size,
                              hipStream_t stream) {
  const float* x    = (const float*)d_in[0];
  const float* mask = (const float*)d_in[1];
  const float* pos  = (const float*)d_in[2];
  const float* gam  = (const float*)d_in[3];
  const float* bet  = (const float*)d_in[4];
  const float* wqkv = (const float*)d_in[5];
  const float* bqkv = (const float*)d_in[6];
  const float* wo   = (const float*)d_in[7];
  const float* bo   = (const float*)d_in[8];
  const float* wt   = (const float*)d_in[9];
  const float* bt   = (const float*)d_in[10];
  float* out = (float*)d_out;

  // workspace: exactly 64 MiB
  char* ws = (char*)d_ws;
  u16* qkvb = (u16*)(ws);                        // 8192 x 3072 bf16 = 50.33 MB
  u16* xp   = (u16*)(ws + (size_t)50331648);     // 8192 x 1024 bf16 = 16.78 MB

  // weight scratch in d_out (dead until kernel 5; 8.4 MB of 33.5 MB):
  u16* wqkv_b = (u16*)d_out;                              // 3072x1024 bf16
  u16* wo_b   = (u16*)((char*)d_out + (size_t)6291456);   // 1024x1024 bf16
  // wt converted into qkvb region after kernel 4 (qkvb dead by then)
  u16* wt_b   = qkvb;

  const int nqkv = 3 * D_ * D_;   // 3,145,728
  const int nd   = D_ * D_;       // 1,048,576

  // 0. convert weights used before kernel 5
  cvt_f32_bf16<<<nqkv / 1024, 256, 0, stream>>>(wqkv, wqkv_b, nqkv);
  cvt_f32_bf16<<<nd   / 1024, 256, 0, stream>>>(wo,   wo_b,   nd);
  // 1. layernorm + pos emb -> xp (bf16)
  ln_pos_kernel<<<B_ * S_, 256, 0, stream>>>(x, pos, gam, bet, xp);
  // 2. qkv = xp @ Wqkv^T + b   [8192,3072] bf16 — 256^2 counted-vmcnt kernel
  gemm_bt256<1, 0, 0><<<dim3(3 * D_ / 256, B_ * S_ / 256), 512, 0, stream>>>(
      xp, wqkv_b, bqkv, nullptr, qkvb, B_ * S_, 3 * D_, D_, D_, 3 * D_);
  // 3. attention; output overwrites the Q-slot of qkvb (stride 3072)
  attn_kernel<<<dim3(S_ / 128, B_ * H_), 256, 0, stream>>>(qkvb, mask);
  // 4. xp = attn_out @ Wo^T + bo + xp   (A = Q-slot of qkvb, lda=3072; in-place)
  gemm_bt<1, 1, 0><<<dim3(D_ / 128, B_ * S_ / 128), 256, 0, stream>>>(
      qkvb, wo_b, bo, xp, xp, B_ * S_, D_, D_, 3 * D_, D_);
  // 4b. convert Wt into (now dead) qkvb region
  cvt_f32_bf16<<<nd / 1024, 256, 0, stream>>>(wt, wt_b, nd);
  // 5. out = xp @ Wt^T + bt  -> fp32 d_out
  gemm_bt<1, 0, 1><<<dim3(D_ / 128, B_ * S_ / 128), 256, 0, stream>>>(
      xp, wt_b, bt, nullptr, out, B_ * S_, D_, D_, D_, D_);
}

// Round 9
// 395.567 us; speedup vs baseline: 1.0172x; 1.0172x over previous
//
#include <hip/hip_runtime.h>
#include <stdint.h>
#include <stddef.h>

typedef unsigned short u16;
typedef __bf16 bf16x8 __attribute__((ext_vector_type(8)));
typedef float floatx4 __attribute__((ext_vector_type(4)));

#define B_  4
#define S_  2048
#define D_  1024
#define H_  16
#define DH_ 64

__device__ __forceinline__ float b2f(u16 u) {
  union { unsigned u; float f; } c; c.u = ((unsigned)u) << 16; return c.f;
}
__device__ __forceinline__ u16 f2b(float f) {
  union { float f; unsigned u; } c; c.f = f;
  unsigned u = c.u;
  u += 0x7fffu + ((u >> 16) & 1u);   // round-to-nearest-even
  return (u16)(u >> 16);
}

// async global->LDS, 16B per lane. LDS dest: wave-uniform base + lane*16.
__device__ __forceinline__ void gld_lds16(const u16* g, u16* l) {
  __builtin_amdgcn_global_load_lds(
      (const __attribute__((address_space(1))) unsigned int*)g,
      (__attribute__((address_space(3))) unsigned int*)l, 16, 0, 0);
}

// pack two f32 -> one u32 of 2 bf16 (no builtin on gfx950; T12 recipe)
__device__ __forceinline__ unsigned cvtpk(float lo, float hi) {
  unsigned r;
  asm("v_cvt_pk_bf16_f32 %0, %1, %2" : "=v"(r) : "v"(lo), "v"(hi));
  return r;
}

// raw v_exp_f32: r = 2^x (ISA §3). Caller pre-scales by log2e.
__device__ __forceinline__ float fexp2(float x) {
  float r; asm("v_exp_f32 %0, %1" : "=v"(r) : "v"(x)); return r;
}

// permlane swaps: diagonal transpose of (reg-index, lane-bit) 2x2
#define PL32(a, b) asm("v_permlane32_swap_b32 %0, %1" : "+v"(a), "+v"(b))
#define PL16(a, b) asm("v_permlane16_swap_b32 %0, %1" : "+v"(a), "+v"(b))

union B8 { unsigned u[4]; bf16x8 v; };

// ---------------------------------------------------------------------------
// Kernel 0: fp32 -> bf16 convert (for weights). n must be a multiple of 4.
// ---------------------------------------------------------------------------
__global__ __launch_bounds__(256) void cvt_f32_bf16(
    const float* __restrict__ src, u16* __restrict__ dst, int n)
{
  int i = (blockIdx.x * 256 + threadIdx.x) * 4;
  if (i >= n) return;
  float4 v = *(const float4*)(src + i);
  u16 o[4] __attribute__((aligned(8)));
  o[0] = f2b(v.x); o[1] = f2b(v.y); o[2] = f2b(v.z); o[3] = f2b(v.w);
  *(uint2*)(dst + i) = *(uint2*)o;
}

// ---------------------------------------------------------------------------
// Kernel 1: LayerNorm + pos_emb add. fp32 in, bf16 out. One block per row.
// ---------------------------------------------------------------------------
__global__ __launch_bounds__(256) void ln_pos_kernel(
    const float* __restrict__ x, const float* __restrict__ pos,
    const float* __restrict__ gamma, const float* __restrict__ beta,
    u16* __restrict__ xp)
{
  const int row = blockIdx.x;
  const int s = row & (S_ - 1);
  const int t = threadIdx.x;
  const int lane = t & 63, w = t >> 6;

  float4 xv = *(const float4*)(x + (size_t)row * D_ + t * 4);
  float f[4] = {xv.x, xv.y, xv.z, xv.w};
  float sum = f[0] + f[1] + f[2] + f[3];
  float sq  = f[0]*f[0] + f[1]*f[1] + f[2]*f[2] + f[3]*f[3];
#pragma unroll
  for (int m = 1; m < 64; m <<= 1) {
    sum += __shfl_xor(sum, m);
    sq  += __shfl_xor(sq, m);
  }
  __shared__ float red[8];
  if (lane == 0) { red[w] = sum; red[4 + w] = sq; }
  __syncthreads();
  sum = red[0] + red[1] + red[2] + red[3];
  sq  = red[4] + red[5] + red[6] + red[7];
  const float mu = sum * (1.f / D_);
  const float rstd = rsqrtf(fmaxf(sq * (1.f / D_) - mu * mu, 0.f) + 1e-5f);

  float4 gv = *(const float4*)(gamma + t * 4);
  float4 bv = *(const float4*)(beta + t * 4);
  float4 pv = *(const float4*)(pos + (size_t)s * D_ + t * 4);
  float g[4] = {gv.x, gv.y, gv.z, gv.w};
  float bb[4] = {bv.x, bv.y, bv.z, bv.w};
  float pp[4] = {pv.x, pv.y, pv.z, pv.w};
  u16 ov[4] __attribute__((aligned(8)));
#pragma unroll
  for (int i = 0; i < 4; ++i)
    ov[i] = f2b((f[i] - mu) * rstd * g[i] + bb[i] + pp[i]);
  *(uint2*)(xp + (size_t)row * D_ + t * 4) = *(uint2*)ov;
}

// ---------------------------------------------------------------------------
// Kernel 2: C[M,N] = A[M,K] @ B[N,K]^T (+bias[N]) (+res[M,N]); bf16 A/B,
// fp32 acc; C stored bf16 (internal) or fp32 (final). A row-stride lda,
// C/res row-stride ldc. 128x128 tile, BK=32, 4 waves, wave = 64x64.
// Double-buffered staging (R6, +3%) + XCD-chunk swizzle (R7). R8's 256^2
// counted-vmcnt variant REGRESSED (+22us: 384-block grid -> 1 block/CU,
// 1.5-wave tail, nothing co-resident to cover barriers) — retired.
// All three GEMMs sit on the m102 shape curve for this structure.
// LDS chunk-rotation swizzle p=(ch+(row>>1))&3 -> conflict-free frag reads.
// No __restrict__ on A/res/C: kernel 4 runs in-place (res==C, elementwise).
// ---------------------------------------------------------------------------
template<int HAS_BIAS, int HAS_RES, int OUT_F32>
__global__ __launch_bounds__(256) void gemm_bt(
    const u16* A, const u16* __restrict__ Bm,
    const float* __restrict__ bias, const u16* res,
    void* Cv, int M, int N, int K, int lda, int ldc)
{
  __shared__ u16 As[2][128 * 32];
  __shared__ u16 Bs[2][128 * 32];
  const int tid = threadIdx.x;
  const int lane = tid & 63, w = tid >> 6;
  const int quad = lane >> 4, l4 = lane & 15;
  const int wm = (w >> 1) * 64, wn = (w & 1) * 64;

  // XCD-aware bijective remap (nwg % 8 == 0 for all launches)
  const int gx = gridDim.x;
  int lin = blockIdx.y * gx + blockIdx.x;
  lin = (lin & 7) * ((gx * gridDim.y) >> 3) + (lin >> 3);
  const int m0 = (lin / gx) * 128, n0 = (lin % gx) * 128;

  const u16* Ag = A + (size_t)m0 * lda;
  const u16* Bg = Bm + (size_t)n0 * K;

  const int s0 = tid, s1 = tid + 256;
  const int r0 = s0 >> 2, c0 = ((s0 & 3) - (r0 >> 1)) & 3;
  const int r1 = s1 >> 2, c1 = ((s1 & 3) - (r1 >> 1)) & 3;
  const int pA = (quad + (l4 >> 1)) & 3;   // frag-read swizzled chunk position

  floatx4 acc[4][4] = {};

  const int nk = K >> 5;
  gld_lds16(Ag + (size_t)r0 * lda + c0 * 8, &As[0][s0 * 8]);
  gld_lds16(Ag + (size_t)r1 * lda + c1 * 8, &As[0][s1 * 8]);
  gld_lds16(Bg + (size_t)r0 * K + c0 * 8, &Bs[0][s0 * 8]);
  gld_lds16(Bg + (size_t)r1 * K + c1 * 8, &Bs[0][s1 * 8]);
  __syncthreads();

  for (int kk = 0; kk < nk; ++kk) {
    const int cur = kk & 1;
    if (kk + 1 < nk) {
      const int k0 = (kk + 1) << 5;
      gld_lds16(Ag + (size_t)r0 * lda + k0 + c0 * 8, &As[cur ^ 1][s0 * 8]);
      gld_lds16(Ag + (size_t)r1 * lda + k0 + c1 * 8, &As[cur ^ 1][s1 * 8]);
      gld_lds16(Bg + (size_t)r0 * K + k0 + c0 * 8, &Bs[cur ^ 1][s0 * 8]);
      gld_lds16(Bg + (size_t)r1 * K + k0 + c1 * 8, &Bs[cur ^ 1][s1 * 8]);
    }
    bf16x8 af[4], bfr[4];
#pragma unroll
    for (int i = 0; i < 4; ++i)
      af[i] = *(const bf16x8*)&As[cur][(wm + i * 16 + l4) * 32 + pA * 8];
#pragma unroll
    for (int j = 0; j < 4; ++j)
      bfr[j] = *(const bf16x8*)&Bs[cur][(wn + j * 16 + l4) * 32 + pA * 8];
#pragma unroll
    for (int i = 0; i < 4; ++i)
#pragma unroll
      for (int j = 0; j < 4; ++j)
        acc[i][j] = __builtin_amdgcn_mfma_f32_16x16x32_bf16(af[i], bfr[j], acc[i][j], 0, 0, 0);
    __syncthreads();   // next tile staged + everyone done reading cur
  }

#pragma unroll
  for (int i = 0; i < 4; ++i) {
#pragma unroll
    for (int j = 0; j < 4; ++j) {
      const int col = n0 + wn + j * 16 + l4;
      float bvv = 0.f;
      if (HAS_BIAS) bvv = bias[col];
#pragma unroll
      for (int r = 0; r < 4; ++r) {
        const int row = m0 + wm + i * 16 + quad * 4 + r;
        float v = acc[i][j][r] + bvv;
        if (HAS_RES) v += b2f(res[(size_t)row * ldc + col]);
        v = fminf(fmaxf(v, -60000.f), 60000.f);  // diagnostic fingerprint; no-op on valid data
        if (OUT_F32) ((float*)Cv)[(size_t)row * ldc + col] = v;
        else         ((u16*)Cv)[(size_t)row * ldc + col] = f2b(v);
      }
    }
  }
}

// ---------------------------------------------------------------------------
// Kernel 3: attention (R7 structure). One block = (b, h, 128 Q rows), 4
// waves, wave owns 32 Q rows. KV tile 64, double-buffered. Swapped QK^T,
// in-register softmax (exp2-fold), cvtpk+permlane P-exchange, MFMA rowsum.
// R9: launch_bounds (256,3)->(256,4) — VGPR 80 < 128 cap, LDS 34KB x 4 =
// 136KB < 160KB, so a 4th resident block is legal; occupancy was 23.6%.
// ---------------------------------------------------------------------------
__global__ __launch_bounds__(256, 4) void attn_kernel(
    u16* qkv, const float* __restrict__ mask)
{
  __shared__ u16 Ks[2][64 * 64];    // 2 x 8 KB, chunk-rotation swizzle
  __shared__ u16 Vt[2][64 * 72];    // 2 x 9 KB, V transposed, +8 pad

  const int tid = threadIdx.x;
  const int lane = tid & 63, w = tid >> 6;
  const int quad = lane >> 4, l4 = lane & 15;
  const int qb = blockIdx.x;           // 0..15
  const int bh = blockIdx.y;           // 0..63
  const int b = bh >> 4, h = bh & 15;
  const int q0 = qb * 128;

  const size_t rstr = 3 * D_;
  u16* qbase = qkv + (size_t)b * S_ * rstr + h * DH_;

  bf16x8 qfrag[2][2];
#pragma unroll
  for (int qi = 0; qi < 2; ++qi) {
    const u16* qp = qbase + (size_t)(q0 + w * 32 + qi * 16 + l4) * rstr + quad * 8;
    qfrag[qi][0] = *(const bf16x8*)(qp);
    qfrag[qi][1] = *(const bf16x8*)(qp + 32);
  }

  const u16* kbase0 = qkv + (size_t)b * S_ * rstr + D_ + h * DH_;
  const u16* vbase0 = kbase0 + D_;
  const int vs = tid & 63, vd0 = (tid >> 6) * 16;

  B8 ones;
  ones.u[0] = ones.u[1] = ones.u[2] = ones.u[3] = 0x3f803f80u;

  floatx4 acc_o[2][4] = {};
  floatx4 acc_l[2] = {};
  u16 vreg[16] __attribute__((aligned(16)));

  {
#pragma unroll
    for (int t = 0; t < 2; ++t) {
      int sidx = tid + t * 256;
      int rr = sidx >> 3, ch = ((sidx & 7) - rr) & 7;
      gld_lds16(kbase0 + (size_t)rr * rstr + ch * 8, &Ks[0][sidx * 8]);
    }
    const u16* vp = vbase0 + (size_t)vs * rstr + vd0;
    *(uint4*)(vreg)     = *(const uint4*)(vp);
    *(uint4*)(vreg + 8) = *(const uint4*)(vp + 8);
  }
  __syncthreads();
#pragma unroll
  for (int d = 0; d < 16; ++d) Vt[0][(vd0 + d) * 72 + vs] = vreg[d];
  __syncthreads();

  int cur = 0;
  for (int j = 0; j < 32; ++j) {
    if (j < 31) {
      const u16* vp = vbase0 + ((size_t)(j + 1) * 64 + vs) * rstr + vd0;
      *(uint4*)(vreg)     = *(const uint4*)(vp);
      *(uint4*)(vreg + 8) = *(const uint4*)(vp + 8);
      const u16* kb = kbase0 + (size_t)(j + 1) * 64 * rstr;
#pragma unroll
      for (int t = 0; t < 2; ++t) {
        int sidx = tid + t * 256;
        int rr = sidx >> 3, ch = ((sidx & 7) - rr) & 7;
        gld_lds16(kb + (size_t)rr * rstr + ch * 8, &Ks[cur ^ 1][sidx * 8]);
      }
    }

    floatx4 accs[2][4] = {};
#pragma unroll
    for (int kc = 0; kc < 2; ++kc)
#pragma unroll
      for (int tj = 0; tj < 4; ++tj) {
        const int rk = tj * 16 + l4;
        bf16x8 kf = *(const bf16x8*)&Ks[cur][rk * 64 + (((kc * 4 + quad) + rk) & 7) * 8];
        accs[0][tj] = __builtin_amdgcn_mfma_f32_16x16x32_bf16(kf, qfrag[0][kc], accs[0][tj], 0, 0, 0);
        accs[1][tj] = __builtin_amdgcn_mfma_f32_16x16x32_bf16(kf, qfrag[1][kc], accs[1][tj], 0, 0, 0);
      }

    const float* mrow = mask + (size_t)b * S_ + j * 64 + quad * 4;
    float mterm[4][4];
#pragma unroll
    for (int tj = 0; tj < 4; ++tj) {
      float4 mv = *(const float4*)(mrow + tj * 16);
      mterm[tj][0] = fmaf(mv.x, -1.44269504f, 1.44269504f);
      mterm[tj][1] = fmaf(mv.y, -1.44269504f, 1.44269504f);
      mterm[tj][2] = fmaf(mv.z, -1.44269504f, 1.44269504f);
      mterm[tj][3] = fmaf(mv.w, -1.44269504f, 1.44269504f);
    }
    unsigned pk[2][4][2];
#pragma unroll
    for (int qi = 0; qi < 2; ++qi) {
#pragma unroll
      for (int tj = 0; tj < 4; ++tj) {
        float p0 = fexp2(fminf(fmaf(accs[qi][tj][0], 0.18033688f, mterm[tj][0]), 43.3f));
        float p1 = fexp2(fminf(fmaf(accs[qi][tj][1], 0.18033688f, mterm[tj][1]), 43.3f));
        float p2 = fexp2(fminf(fmaf(accs[qi][tj][2], 0.18033688f, mterm[tj][2]), 43.3f));
        float p3 = fexp2(fminf(fmaf(accs[qi][tj][3], 0.18033688f, mterm[tj][3]), 43.3f));
        pk[qi][tj][0] = cvtpk(p0, p1);
        pk[qi][tj][1] = cvtpk(p2, p3);
      }
    }

#pragma unroll
    for (int kc = 0; kc < 2; ++kc) {
      bf16x8 bfr[4];
#pragma unroll
      for (int tn = 0; tn < 4; ++tn)
        bfr[tn] = *(const bf16x8*)&Vt[cur][(tn * 16 + l4) * 72 + kc * 32 + quad * 8];
#pragma unroll
      for (int qi = 0; qi < 2; ++qi) {
        unsigned x0 = pk[qi][2 * kc][0], x1 = pk[qi][2 * kc + 1][0];
        unsigned y0 = pk[qi][2 * kc][1], y1 = pk[qi][2 * kc + 1][1];
        PL32(x0, x1); PL32(y0, y1);
        PL16(x0, x1); PL16(y0, y1);
        B8 pa; pa.u[0] = x0; pa.u[1] = y0; pa.u[2] = x1; pa.u[3] = y1;
        __builtin_amdgcn_s_setprio(1);
#pragma unroll
        for (int tn = 0; tn < 4; ++tn)
          acc_o[qi][tn] = __builtin_amdgcn_mfma_f32_16x16x32_bf16(pa.v, bfr[tn], acc_o[qi][tn], 0, 0, 0);
        acc_l[qi] = __builtin_amdgcn_mfma_f32_16x16x32_bf16(pa.v, ones.v, acc_l[qi], 0, 0, 0);
        __builtin_amdgcn_s_setprio(0);
      }
    }

    if (j < 31) {
#pragma unroll
      for (int d = 0; d < 16; ++d) Vt[cur ^ 1][(vd0 + d) * 72 + vs] = vreg[d];
    }

    __syncthreads();
    cur ^= 1;
  }

#pragma unroll
  for (int qi = 0; qi < 2; ++qi) {
    float inv[4];
#pragma unroll
    for (int r = 0; r < 4; ++r) inv[r] = 1.0f / acc_l[qi][r];
#pragma unroll
    for (int tn = 0; tn < 4; ++tn) {
#pragma unroll
      for (int r = 0; r < 4; ++r) {
        const int row = q0 + w * 32 + qi * 16 + quad * 4 + r;
        const int col = h * DH_ + tn * 16 + l4;
        qkv[((size_t)b * S_ + row) * rstr + col] = f2b(acc_o[qi][tn][r] * inv[r]);
      }
    }
  }
}

// ---------------------------------------------------------------------------
extern "C" void kernel_launch(void* const* d_in, const int* in_sizes, int n_in,
                              void* d_out, int out_size, void* d_ws, size_t ws_size,
                              hipStream_t stream) {
  const float* x    = (const float*)d_in[0];
  const float* mask = (const float*)d_in[1];
  const float* pos  = (const float*)d_in[2];
  const float* gam  = (const float*)d_in[3];
  const float* bet  = (const float*)d_in[4];
  const float* wqkv = (const float*)d_in[5];
  const float* bqkv = (const float*)d_in[6];
  const float* wo   = (const float*)d_in[7];
  const float* bo   = (const float*)d_in[8];
  const float* wt   = (const float*)d_in[9];
  const float* bt   = (const float*)d_in[10];
  float* out = (float*)d_out;

  // workspace: exactly 64 MiB
  char* ws = (char*)d_ws;
  u16* qkvb = (u16*)(ws);                        // 8192 x 3072 bf16 = 50.33 MB
  u16* xp   = (u16*)(ws + (size_t)50331648);     // 8192 x 1024 bf16 = 16.78 MB

  // weight scratch in d_out (dead until kernel 5; 8.4 MB of 33.5 MB):
  u16* wqkv_b = (u16*)d_out;                              // 3072x1024 bf16
  u16* wo_b   = (u16*)((char*)d_out + (size_t)6291456);   // 1024x1024 bf16
  // wt converted into qkvb region after kernel 4 (qkvb dead by then)
  u16* wt_b   = qkvb;

  const int nqkv = 3 * D_ * D_;   // 3,145,728
  const int nd   = D_ * D_;       // 1,048,576

  // 0. convert weights used before kernel 5
  cvt_f32_bf16<<<nqkv / 1024, 256, 0, stream>>>(wqkv, wqkv_b, nqkv);
  cvt_f32_bf16<<<nd   / 1024, 256, 0, stream>>>(wo,   wo_b,   nd);
  // 1. layernorm + pos emb -> xp (bf16)
  ln_pos_kernel<<<B_ * S_, 256, 0, stream>>>(x, pos, gam, bet, xp);
  // 2. qkv = xp @ Wqkv^T + b   [8192,3072] bf16
  gemm_bt<1, 0, 0><<<dim3(3 * D_ / 128, B_ * S_ / 128), 256, 0, stream>>>(
      xp, wqkv_b, bqkv, nullptr, qkvb, B_ * S_, 3 * D_, D_, D_, 3 * D_);
  // 3. attention; output overwrites the Q-slot of qkvb (stride 3072)
  attn_kernel<<<dim3(S_ / 128, B_ * H_), 256, 0, stream>>>(qkvb, mask);
  // 4. xp = attn_out @ Wo^T + bo + xp   (A = Q-slot of qkvb, lda=3072; in-place)
  gemm_bt<1, 1, 0><<<dim3(D_ / 128, B_ * S_ / 128), 256, 0, stream>>>(
      qkvb, wo_b, bo, xp, xp, B_ * S_, D_, D_, 3 * D_, D_);
  // 4b. convert Wt into (now dead) qkvb region
  cvt_f32_bf16<<<nd / 1024, 256, 0, stream>>>(wt, wt_b, nd);
  // 5. out = xp @ Wt^T + bt  -> fp32 d_out
  gemm_bt<1, 0, 1><<<dim3(D_ / 128, B_ * S_ / 128), 256, 0, stream>>>(
      xp, wt_b, bt, nullptr, out, B_ * S_, D_, D_, D_, D_);
}

// Round 10
// 387.210 us; speedup vs baseline: 1.0391x; 1.0216x over previous
//
#include <hip/hip_runtime.h>
#include <stdint.h>
#include <stddef.h>

typedef unsigned short u16;
typedef __bf16 bf16x8 __attribute__((ext_vector_type(8)));
typedef float floatx4 __attribute__((ext_vector_type(4)));

#define B_  4
#define S_  2048
#define D_  1024
#define H_  16
#define DH_ 64

__device__ __forceinline__ float b2f(u16 u) {
  union { unsigned u; float f; } c; c.u = ((unsigned)u) << 16; return c.f;
}
__device__ __forceinline__ u16 f2b(float f) {
  union { float f; unsigned u; } c; c.f = f;
  unsigned u = c.u;
  u += 0x7fffu + ((u >> 16) & 1u);   // round-to-nearest-even
  return (u16)(u >> 16);
}

// async global->LDS, 16B per lane. LDS dest: wave-uniform base + lane*16.
__device__ __forceinline__ void gld_lds16(const u16* g, u16* l) {
  __builtin_amdgcn_global_load_lds(
      (const __attribute__((address_space(1))) unsigned int*)g,
      (__attribute__((address_space(3))) unsigned int*)l, 16, 0, 0);
}

// pack two f32 -> one u32 of 2 bf16 (no builtin on gfx950; T12 recipe)
__device__ __forceinline__ unsigned cvtpk(float lo, float hi) {
  unsigned r;
  asm("v_cvt_pk_bf16_f32 %0, %1, %2" : "=v"(r) : "v"(lo), "v"(hi));
  return r;
}

// raw v_exp_f32: r = 2^x (ISA §3). Caller pre-scales by log2e.
__device__ __forceinline__ float fexp2(float x) {
  float r; asm("v_exp_f32 %0, %1" : "=v"(r) : "v"(x)); return r;
}

// permlane swaps: diagonal transpose of (reg-index, lane-bit) 2x2
#define PL32(a, b) asm("v_permlane32_swap_b32 %0, %1" : "+v"(a), "+v"(b))
#define PL16(a, b) asm("v_permlane16_swap_b32 %0, %1" : "+v"(a), "+v"(b))

union B8 { unsigned u[4]; bf16x8 v; };

// ---------------------------------------------------------------------------
// Kernel 0: fp32 -> bf16 convert (for weights). n must be a multiple of 4.
// ---------------------------------------------------------------------------
__global__ __launch_bounds__(256) void cvt_f32_bf16(
    const float* __restrict__ src, u16* __restrict__ dst, int n)
{
  int i = (blockIdx.x * 256 + threadIdx.x) * 4;
  if (i >= n) return;
  float4 v = *(const float4*)(src + i);
  u16 o[4] __attribute__((aligned(8)));
  o[0] = f2b(v.x); o[1] = f2b(v.y); o[2] = f2b(v.z); o[3] = f2b(v.w);
  *(uint2*)(dst + i) = *(uint2*)o;
}

// ---------------------------------------------------------------------------
// Kernel 1: LayerNorm + pos_emb add. fp32 in, bf16 out. One block per row.
// ---------------------------------------------------------------------------
__global__ __launch_bounds__(256) void ln_pos_kernel(
    const float* __restrict__ x, const float* __restrict__ pos,
    const float* __restrict__ gamma, const float* __restrict__ beta,
    u16* __restrict__ xp)
{
  const int row = blockIdx.x;
  const int s = row & (S_ - 1);
  const int t = threadIdx.x;
  const int lane = t & 63, w = t >> 6;

  float4 xv = *(const float4*)(x + (size_t)row * D_ + t * 4);
  float f[4] = {xv.x, xv.y, xv.z, xv.w};
  float sum = f[0] + f[1] + f[2] + f[3];
  float sq  = f[0]*f[0] + f[1]*f[1] + f[2]*f[2] + f[3]*f[3];
#pragma unroll
  for (int m = 1; m < 64; m <<= 1) {
    sum += __shfl_xor(sum, m);
    sq  += __shfl_xor(sq, m);
  }
  __shared__ float red[8];
  if (lane == 0) { red[w] = sum; red[4 + w] = sq; }
  __syncthreads();
  sum = red[0] + red[1] + red[2] + red[3];
  sq  = red[4] + red[5] + red[6] + red[7];
  const float mu = sum * (1.f / D_);
  const float rstd = rsqrtf(fmaxf(sq * (1.f / D_) - mu * mu, 0.f) + 1e-5f);

  float4 gv = *(const float4*)(gamma + t * 4);
  float4 bv = *(const float4*)(beta + t * 4);
  float4 pv = *(const float4*)(pos + (size_t)s * D_ + t * 4);
  float g[4] = {gv.x, gv.y, gv.z, gv.w};
  float bb[4] = {bv.x, bv.y, bv.z, bv.w};
  float pp[4] = {pv.x, pv.y, pv.z, pv.w};
  u16 ov[4] __attribute__((aligned(8)));
#pragma unroll
  for (int i = 0; i < 4; ++i)
    ov[i] = f2b((f[i] - mu) * rstd * g[i] + bb[i] + pp[i]);
  *(uint2*)(xp + (size_t)row * D_ + t * 4) = *(uint2*)ov;
}

// ---------------------------------------------------------------------------
// Kernel 2: C[M,N] = A[M,K] @ B[N,K]^T (+bias[N]) (+res[M,N]); bf16 A/B,
// fp32 acc; C stored bf16 (internal) or fp32 (final). A row-stride lda,
// C/res row-stride ldc. 128x128 tile, BK=32, 4 waves, wave = 64x64.
// Double-buffered staging (R6) + XCD-chunk swizzle (R7). 256^2 counted-vmcnt
// variant retired (R8: 384-block grid -> 1 block/CU, 1.5-wave tail).
// LDS chunk-rotation swizzle p=(ch+(row>>1))&3 -> conflict-free frag reads.
// No __restrict__ on A/res/C: kernel 4 runs in-place (res==C, elementwise).
// ---------------------------------------------------------------------------
template<int HAS_BIAS, int HAS_RES, int OUT_F32>
__global__ __launch_bounds__(256) void gemm_bt(
    const u16* A, const u16* __restrict__ Bm,
    const float* __restrict__ bias, const u16* res,
    void* Cv, int M, int N, int K, int lda, int ldc)
{
  __shared__ u16 As[2][128 * 32];
  __shared__ u16 Bs[2][128 * 32];
  const int tid = threadIdx.x;
  const int lane = tid & 63, w = tid >> 6;
  const int quad = lane >> 4, l4 = lane & 15;
  const int wm = (w >> 1) * 64, wn = (w & 1) * 64;

  // XCD-aware bijective remap (nwg % 8 == 0 for all launches)
  const int gx = gridDim.x;
  int lin = blockIdx.y * gx + blockIdx.x;
  lin = (lin & 7) * ((gx * gridDim.y) >> 3) + (lin >> 3);
  const int m0 = (lin / gx) * 128, n0 = (lin % gx) * 128;

  const u16* Ag = A + (size_t)m0 * lda;
  const u16* Bg = Bm + (size_t)n0 * K;

  const int s0 = tid, s1 = tid + 256;
  const int r0 = s0 >> 2, c0 = ((s0 & 3) - (r0 >> 1)) & 3;
  const int r1 = s1 >> 2, c1 = ((s1 & 3) - (r1 >> 1)) & 3;
  const int pA = (quad + (l4 >> 1)) & 3;   // frag-read swizzled chunk position

  floatx4 acc[4][4] = {};

  const int nk = K >> 5;
  gld_lds16(Ag + (size_t)r0 * lda + c0 * 8, &As[0][s0 * 8]);
  gld_lds16(Ag + (size_t)r1 * lda + c1 * 8, &As[0][s1 * 8]);
  gld_lds16(Bg + (size_t)r0 * K + c0 * 8, &Bs[0][s0 * 8]);
  gld_lds16(Bg + (size_t)r1 * K + c1 * 8, &Bs[0][s1 * 8]);
  __syncthreads();

  for (int kk = 0; kk < nk; ++kk) {
    const int cur = kk & 1;
    if (kk + 1 < nk) {
      const int k0 = (kk + 1) << 5;
      gld_lds16(Ag + (size_t)r0 * lda + k0 + c0 * 8, &As[cur ^ 1][s0 * 8]);
      gld_lds16(Ag + (size_t)r1 * lda + k0 + c1 * 8, &As[cur ^ 1][s1 * 8]);
      gld_lds16(Bg + (size_t)r0 * K + k0 + c0 * 8, &Bs[cur ^ 1][s0 * 8]);
      gld_lds16(Bg + (size_t)r1 * K + k0 + c1 * 8, &Bs[cur ^ 1][s1 * 8]);
    }
    bf16x8 af[4], bfr[4];
#pragma unroll
    for (int i = 0; i < 4; ++i)
      af[i] = *(const bf16x8*)&As[cur][(wm + i * 16 + l4) * 32 + pA * 8];
#pragma unroll
    for (int j = 0; j < 4; ++j)
      bfr[j] = *(const bf16x8*)&Bs[cur][(wn + j * 16 + l4) * 32 + pA * 8];
#pragma unroll
    for (int i = 0; i < 4; ++i)
#pragma unroll
      for (int j = 0; j < 4; ++j)
        acc[i][j] = __builtin_amdgcn_mfma_f32_16x16x32_bf16(af[i], bfr[j], acc[i][j], 0, 0, 0);
    __syncthreads();   // next tile staged + everyone done reading cur
  }

#pragma unroll
  for (int i = 0; i < 4; ++i) {
#pragma unroll
    for (int j = 0; j < 4; ++j) {
      const int col = n0 + wn + j * 16 + l4;
      float bvv = 0.f;
      if (HAS_BIAS) bvv = bias[col];
#pragma unroll
      for (int r = 0; r < 4; ++r) {
        const int row = m0 + wm + i * 16 + quad * 4 + r;
        float v = acc[i][j][r] + bvv;
        if (HAS_RES) v += b2f(res[(size_t)row * ldc + col]);
        v = fminf(fmaxf(v, -60000.f), 60000.f);  // diagnostic fingerprint; no-op on valid data
        if (OUT_F32) ((float*)Cv)[(size_t)row * ldc + col] = v;
        else         ((u16*)Cv)[(size_t)row * ldc + col] = f2b(v);
      }
    }
  }
}

// ---------------------------------------------------------------------------
// Kernel 3: attention (R7 structure, measured best: 144.5 us). One block =
// (b, h, 128 Q rows), 4 waves, wave owns 32 Q rows. KV tile 64, dbuf.
// Swapped QK^T, in-register softmax (exp2-fold), cvtpk+permlane P-exchange,
// MFMA rowsum. launch_bounds (256,3): R9's (256,4) capped VGPR at 64 ->
// scratch spills (WRITE_SIZE 16->27 MB) -> +16us despite occupancy 24->40%.
// The kernel's natural 80 VGPR must not be squeezed.
// ---------------------------------------------------------------------------
__global__ __launch_bounds__(256, 3) void attn_kernel(
    u16* qkv, const float* __restrict__ mask)
{
  __shared__ u16 Ks[2][64 * 64];    // 2 x 8 KB, chunk-rotation swizzle
  __shared__ u16 Vt[2][64 * 72];    // 2 x 9 KB, V transposed, +8 pad

  const int tid = threadIdx.x;
  const int lane = tid & 63, w = tid >> 6;
  const int quad = lane >> 4, l4 = lane & 15;
  const int qb = blockIdx.x;           // 0..15
  const int bh = blockIdx.y;           // 0..63
  const int b = bh >> 4, h = bh & 15;
  const int q0 = qb * 128;

  const size_t rstr = 3 * D_;
  u16* qbase = qkv + (size_t)b * S_ * rstr + h * DH_;

  bf16x8 qfrag[2][2];
#pragma unroll
  for (int qi = 0; qi < 2; ++qi) {
    const u16* qp = qbase + (size_t)(q0 + w * 32 + qi * 16 + l4) * rstr + quad * 8;
    qfrag[qi][0] = *(const bf16x8*)(qp);
    qfrag[qi][1] = *(const bf16x8*)(qp + 32);
  }

  const u16* kbase0 = qkv + (size_t)b * S_ * rstr + D_ + h * DH_;
  const u16* vbase0 = kbase0 + D_;
  const int vs = tid & 63, vd0 = (tid >> 6) * 16;

  B8 ones;
  ones.u[0] = ones.u[1] = ones.u[2] = ones.u[3] = 0x3f803f80u;

  floatx4 acc_o[2][4] = {};
  floatx4 acc_l[2] = {};
  u16 vreg[16] __attribute__((aligned(16)));

  {
#pragma unroll
    for (int t = 0; t < 2; ++t) {
      int sidx = tid + t * 256;
      int rr = sidx >> 3, ch = ((sidx & 7) - rr) & 7;
      gld_lds16(kbase0 + (size_t)rr * rstr + ch * 8, &Ks[0][sidx * 8]);
    }
    const u16* vp = vbase0 + (size_t)vs * rstr + vd0;
    *(uint4*)(vreg)     = *(const uint4*)(vp);
    *(uint4*)(vreg + 8) = *(const uint4*)(vp + 8);
  }
  __syncthreads();
#pragma unroll
  for (int d = 0; d < 16; ++d) Vt[0][(vd0 + d) * 72 + vs] = vreg[d];
  __syncthreads();

  int cur = 0;
  for (int j = 0; j < 32; ++j) {
    if (j < 31) {
      const u16* vp = vbase0 + ((size_t)(j + 1) * 64 + vs) * rstr + vd0;
      *(uint4*)(vreg)     = *(const uint4*)(vp);
      *(uint4*)(vreg + 8) = *(const uint4*)(vp + 8);
      const u16* kb = kbase0 + (size_t)(j + 1) * 64 * rstr;
#pragma unroll
      for (int t = 0; t < 2; ++t) {
        int sidx = tid + t * 256;
        int rr = sidx >> 3, ch = ((sidx & 7) - rr) & 7;
        gld_lds16(kb + (size_t)rr * rstr + ch * 8, &Ks[cur ^ 1][sidx * 8]);
      }
    }

    floatx4 accs[2][4] = {};
#pragma unroll
    for (int kc = 0; kc < 2; ++kc)
#pragma unroll
      for (int tj = 0; tj < 4; ++tj) {
        const int rk = tj * 16 + l4;
        bf16x8 kf = *(const bf16x8*)&Ks[cur][rk * 64 + (((kc * 4 + quad) + rk) & 7) * 8];
        accs[0][tj] = __builtin_amdgcn_mfma_f32_16x16x32_bf16(kf, qfrag[0][kc], accs[0][tj], 0, 0, 0);
        accs[1][tj] = __builtin_amdgcn_mfma_f32_16x16x32_bf16(kf, qfrag[1][kc], accs[1][tj], 0, 0, 0);
      }

    const float* mrow = mask + (size_t)b * S_ + j * 64 + quad * 4;
    float mterm[4][4];
#pragma unroll
    for (int tj = 0; tj < 4; ++tj) {
      float4 mv = *(const float4*)(mrow + tj * 16);
      mterm[tj][0] = fmaf(mv.x, -1.44269504f, 1.44269504f);
      mterm[tj][1] = fmaf(mv.y, -1.44269504f, 1.44269504f);
      mterm[tj][2] = fmaf(mv.z, -1.44269504f, 1.44269504f);
      mterm[tj][3] = fmaf(mv.w, -1.44269504f, 1.44269504f);
    }
    unsigned pk[2][4][2];
#pragma unroll
    for (int qi = 0; qi < 2; ++qi) {
#pragma unroll
      for (int tj = 0; tj < 4; ++tj) {
        float p0 = fexp2(fminf(fmaf(accs[qi][tj][0], 0.18033688f, mterm[tj][0]), 43.3f));
        float p1 = fexp2(fminf(fmaf(accs[qi][tj][1], 0.18033688f, mterm[tj][1]), 43.3f));
        float p2 = fexp2(fminf(fmaf(accs[qi][tj][2], 0.18033688f, mterm[tj][2]), 43.3f));
        float p3 = fexp2(fminf(fmaf(accs[qi][tj][3], 0.18033688f, mterm[tj][3]), 43.3f));
        pk[qi][tj][0] = cvtpk(p0, p1);
        pk[qi][tj][1] = cvtpk(p2, p3);
      }
    }

#pragma unroll
    for (int kc = 0; kc < 2; ++kc) {
      bf16x8 bfr[4];
#pragma unroll
      for (int tn = 0; tn < 4; ++tn)
        bfr[tn] = *(const bf16x8*)&Vt[cur][(tn * 16 + l4) * 72 + kc * 32 + quad * 8];
#pragma unroll
      for (int qi = 0; qi < 2; ++qi) {
        unsigned x0 = pk[qi][2 * kc][0], x1 = pk[qi][2 * kc + 1][0];
        unsigned y0 = pk[qi][2 * kc][1], y1 = pk[qi][2 * kc + 1][1];
        PL32(x0, x1); PL32(y0, y1);
        PL16(x0, x1); PL16(y0, y1);
        B8 pa; pa.u[0] = x0; pa.u[1] = y0; pa.u[2] = x1; pa.u[3] = y1;
        __builtin_amdgcn_s_setprio(1);
#pragma unroll
        for (int tn = 0; tn < 4; ++tn)
          acc_o[qi][tn] = __builtin_amdgcn_mfma_f32_16x16x32_bf16(pa.v, bfr[tn], acc_o[qi][tn], 0, 0, 0);
        acc_l[qi] = __builtin_amdgcn_mfma_f32_16x16x32_bf16(pa.v, ones.v, acc_l[qi], 0, 0, 0);
        __builtin_amdgcn_s_setprio(0);
      }
    }

    if (j < 31) {
#pragma unroll
      for (int d = 0; d < 16; ++d) Vt[cur ^ 1][(vd0 + d) * 72 + vs] = vreg[d];
    }

    __syncthreads();
    cur ^= 1;
  }

#pragma unroll
  for (int qi = 0; qi < 2; ++qi) {
    float inv[4];
#pragma unroll
    for (int r = 0; r < 4; ++r) inv[r] = 1.0f / acc_l[qi][r];
#pragma unroll
    for (int tn = 0; tn < 4; ++tn) {
#pragma unroll
      for (int r = 0; r < 4; ++r) {
        const int row = q0 + w * 32 + qi * 16 + quad * 4 + r;
        const int col = h * DH_ + tn * 16 + l4;
        qkv[((size_t)b * S_ + row) * rstr + col] = f2b(acc_o[qi][tn][r] * inv[r]);
      }
    }
  }
}

// ---------------------------------------------------------------------------
extern "C" void kernel_launch(void* const* d_in, const int* in_sizes, int n_in,
                              void* d_out, int out_size, void* d_ws, size_t ws_size,
                              hipStream_t stream) {
  const float* x    = (const float*)d_in[0];
  const float* mask = (const float*)d_in[1];
  const float* pos  = (const float*)d_in[2];
  const float* gam  = (const float*)d_in[3];
  const float* bet  = (const float*)d_in[4];
  const float* wqkv = (const float*)d_in[5];
  const float* bqkv = (const float*)d_in[6];
  const float* wo   = (const float*)d_in[7];
  const float* bo   = (const float*)d_in[8];
  const float* wt   = (const float*)d_in[9];
  const float* bt   = (const float*)d_in[10];
  float* out = (float*)d_out;

  // workspace: exactly 64 MiB
  char* ws = (char*)d_ws;
  u16* qkvb = (u16*)(ws);                        // 8192 x 3072 bf16 = 50.33 MB
  u16* xp   = (u16*)(ws + (size_t)50331648);     // 8192 x 1024 bf16 = 16.78 MB

  // weight scratch in d_out (dead until kernel 5; 8.4 MB of 33.5 MB):
  u16* wqkv_b = (u16*)d_out;                              // 3072x1024 bf16
  u16* wo_b   = (u16*)((char*)d_out + (size_t)6291456);   // 1024x1024 bf16
  // wt converted into qkvb region after kernel 4 (qkvb dead by then)
  u16* wt_b   = qkvb;

  const int nqkv = 3 * D_ * D_;   // 3,145,728
  const int nd   = D_ * D_;       // 1,048,576

  // 0. convert weights used before kernel 5
  cvt_f32_bf16<<<nqkv / 1024, 256, 0, stream>>>(wqkv, wqkv_b, nqkv);
  cvt_f32_bf16<<<nd   / 1024, 256, 0, stream>>>(wo,   wo_b,   nd);
  // 1. layernorm + pos emb -> xp (bf16)
  ln_pos_kernel<<<B_ * S_, 256, 0, stream>>>(x, pos, gam, bet, xp);
  // 2. qkv = xp @ Wqkv^T + b   [8192,3072] bf16
  gemm_bt<1, 0, 0><<<dim3(3 * D_ / 128, B_ * S_ / 128), 256, 0, stream>>>(
      xp, wqkv_b, bqkv, nullptr, qkvb, B_ * S_, 3 * D_, D_, D_, 3 * D_);
  // 3. attention; output overwrites the Q-slot of qkvb (stride 3072)
  attn_kernel<<<dim3(S_ / 128, B_ * H_), 256, 0, stream>>>(qkvb, mask);
  // 4. xp = attn_out @ Wo^T + bo + xp   (A = Q-slot of qkvb, lda=3072; in-place)
  gemm_bt<1, 1, 0><<<dim3(D_ / 128, B_ * S_ / 128), 256, 0, stream>>>(
      qkvb, wo_b, bo, xp, xp, B_ * S_, D_, D_, 3 * D_, D_);
  // 4b. convert Wt into (now dead) qkvb region
  cvt_f32_bf16<<<nd / 1024, 256, 0, stream>>>(wt, wt_b, nd);
  // 5. out = xp @ Wt^T + bt  -> fp32 d_out
  gemm_bt<1, 0, 1><<<dim3(D_ / 128, B_ * S_ / 128), 256, 0, stream>>>(
      xp, wt_b, bt, nullptr, out, B_ * S_, D_, D_, D_, D_);
}